// Round 4
// baseline (851.341 us; speedup 1.0000x reference)
//
#include <hip/hip_runtime.h>

typedef unsigned short u16;
typedef __bf16 bf16x8 __attribute__((ext_vector_type(8)));
typedef float f32x4 __attribute__((ext_vector_type(4)));

#define NW 4096      // B*W words
#define HDIM 512
#define EDIM 128
#define G4 2048      // 4*H
#define LMAX 16
#define KREC 640     // E + H

__device__ __forceinline__ u16 f2bf(float f) {
  unsigned u = __float_as_uint(f);
  u += 0x7FFFu + ((u >> 16) & 1u);
  return (u16)(u >> 16);
}

__device__ __forceinline__ float sigf(float x) { return 1.f / (1.f + __expf(-x)); }
__device__ __forceinline__ float tanha(float x) {
  float ax = fabsf(x);
  float e = __expf(2.f * ax);
  float t = 1.f - 2.f / (e + 1.f);
  return x < 0.f ? -t : t;
}

__device__ __forceinline__ void gload16(const void* g, void* l) {
  __builtin_amdgcn_global_load_lds((const __attribute__((address_space(1))) void*)g,
                                   (__attribute__((address_space(3))) void*)l, 16, 0, 0);
}

union V16 { int4 i; bf16x8 b; };
__device__ __forceinline__ bf16x8 ldfrag(const u16* p) {
  V16 v; v.i = *(const int4*)p; return v.b;
}

// ---------------- sort: bucket words by length (descending) ----------------
// perm[slot] = orig word; lens_s[slot] = len; nactive[t] = #words with len > t
__global__ __launch_bounds__(256) void sort_kernel(
    const int* __restrict__ lens,
    int* __restrict__ perm, int* __restrict__ lens_s, int* __restrict__ nactive) {
  __shared__ int cnt[LMAX + 1];     // counts for len 1..16
  __shared__ int start[LMAX + 1];   // start[l] = sum of counts of lens > l
  __shared__ int cursor[LMAX + 1];
  int tid = threadIdx.x;
  if (tid <= LMAX) cnt[tid] = 0;
  __syncthreads();
  for (int w = tid; w < NW; w += 256) atomicAdd(&cnt[lens[w]], 1);
  __syncthreads();
  if (tid == 0) {
    int acc = 0;
    for (int l = LMAX; l >= 1; --l) { start[l] = acc; acc += cnt[l]; }
    start[0] = acc;                 // == NW
  }
  __syncthreads();
  if (tid <= LMAX) cursor[tid] = start[tid];
  if (tid < LMAX) nactive[tid] = start[tid];   // nactive[t] = #len > t, t=0..15
  __syncthreads();
  for (int w = tid; w < NW; w += 256) {
    int l = lens[w];
    int pos = atomicAdd(&cursor[l], 1);
    perm[pos] = w;
    lens_s[pos] = l;
  }
}

// ---------------- prep: weights (permuted, bf16), biases, Wp, X gathers ----------------
// Job A: Wcat  2*2048*80 8-elem tasks        [0, 327680)
// Job B: bcat  2*2048 tasks                  [327680, 331776)
// Job C: Wpb   512*128 8-elem tasks          [331776, 397312)
// Job D: X     16*4096*16 8-elem tasks (f+b) [397312, 1445888)  -- sorted word space
__global__ __launch_bounds__(256) void prep_kernel(
    const int* __restrict__ chars,
    const int* __restrict__ perm, const int* __restrict__ lens_s,
    const float* __restrict__ emb,
    const float* __restrict__ Wih_f, const float* __restrict__ Whh_f,
    const float* __restrict__ bih_f, const float* __restrict__ bhh_f,
    const float* __restrict__ Wih_b, const float* __restrict__ Whh_b,
    const float* __restrict__ bih_b, const float* __restrict__ bhh_b,
    const float* __restrict__ Wp,
    u16* __restrict__ Wcat, float* __restrict__ bcat, u16* __restrict__ Wpb,
    u16* __restrict__ Xf, u16* __restrict__ Xb) {
  int idx = blockIdx.x * 256 + threadIdx.x;
  if (idx < 327680) {                       // Wcat
    int d = idx / (2048 * 80);
    int r = idx % (2048 * 80);
    int p = r / 80, c8 = r % 80;
    int unit = p >> 2, gate = p & 3;
    int orig = gate * 512 + unit;
    const float* Wih = d ? Wih_b : Wih_f;
    const float* Whh = d ? Whh_b : Whh_f;
    int k = c8 * 8;
    const float* src = (k < EDIM) ? (Wih + (size_t)orig * EDIM + k)
                                  : (Whh + (size_t)orig * HDIM + (k - EDIM));
    union { u16 u[8]; int4 v; } t;
#pragma unroll
    for (int j = 0; j < 8; ++j) t.u[j] = f2bf(src[j]);
    *(int4*)(Wcat + ((size_t)d * G4 + p) * KREC + k) = t.v;
  } else if (idx < 331776) {                // bcat
    int r = idx - 327680;
    int d = r / G4, p = r % G4;
    int unit = p >> 2, gate = p & 3;
    int orig = gate * 512 + unit;
    bcat[d * G4 + p] = d ? (bih_b[orig] + bhh_b[orig]) : (bih_f[orig] + bhh_f[orig]);
  } else if (idx < 397312) {                // Wpb
    int r = idx - 331776;
    int row = r >> 7, c8 = r & 127;
    union { u16 u[8]; int4 v; } t;
#pragma unroll
    for (int j = 0; j < 8; ++j) t.u[j] = f2bf(Wp[(size_t)row * 1024 + c8 * 8 + j]);
    *(int4*)(Wpb + (size_t)row * 1024 + c8 * 8) = t.v;
  } else {                                  // X gathers (sorted space)
    int r = idx - 397312;
    int tw = r >> 4, e8 = (r & 15) * 8;
    int t = tw >> 12, s = tw & (NW - 1);
    int w = perm[s];
    int len = lens_s[s];
    int cf = chars[w * LMAX + t];
    int tb = len - 1 - t; if (tb < 0) tb = 0;
    int cb = chars[w * LMAX + tb];
    union { u16 u[8]; int4 v; } vf, vb;
#pragma unroll
    for (int j = 0; j < 8; ++j) {
      vf.u[j] = f2bf(emb[(size_t)cf * EDIM + e8 + j]);
      vb.u[j] = f2bf(emb[(size_t)cb * EDIM + e8 + j]);
    }
    size_t o = ((size_t)t * NW + s) * EDIM + e8;
    *(int4*)(Xf + o) = vf.v;
    *(int4*)(Xb + o) = vb.v;
  }
}

// ---------------- per-step fused GEMM + LSTM update (sorted word space) ----------------
// C^T layout: M = 2048 permuted gate-rows (4*unit+gate), N = active words, K = 640.
// grid: x = word tiles (32, early-exit past nactive), y = gate-row tiles (16), z = dir
__global__ __launch_bounds__(256) void step_kernel(
    const u16* __restrict__ Wcat, const float* __restrict__ bcat,
    const u16* __restrict__ Xf, const u16* __restrict__ Xb,
    const u16* __restrict__ hprev, u16* __restrict__ hnext,
    float* __restrict__ cst, u16* __restrict__ concat,
    const int* __restrict__ perm, const int* __restrict__ lens_s,
    const int* __restrict__ nactive, int t, int nIter, int first) {
  const int w0 = blockIdx.x * 128;   // sorted word base
  if (w0 >= nactive[t]) return;      // whole tile inactive at this step

  __shared__ u16 ldsA[128 * 64];
  __shared__ u16 ldsB[128 * 64];

  const int tid = threadIdx.x;
  const int lane = tid & 63;
  const int wid = tid >> 6;
  const int wm = wid >> 1, wn = wid & 1;
  const int dir = blockIdx.z;
  const int m0 = blockIdx.y * 128;   // gate-row base

  const u16* Wd = Wcat + (size_t)dir * G4 * KREC;
  const u16* Xd = dir ? Xb : Xf;
  const u16* hpd = hprev + (size_t)dir * NW * HDIM;

  f32x4 acc[4][4];
#pragma unroll
  for (int i = 0; i < 4; ++i)
#pragma unroll
    for (int j = 0; j < 4; ++j) acc[i][j] = (f32x4){0.f, 0.f, 0.f, 0.f};

  const int srow = tid >> 3;     // 0..31
  const int c8 = tid & 7;

  for (int kit = 0; kit < nIter; ++kit) {
    const int k0 = kit * 64;
#pragma unroll
    for (int s = 0; s < 4; ++s) {
      int rr = s * 32 + srow;
      gload16(Wd + (size_t)(m0 + rr) * KREC + k0 + c8 * 8, ldsA + rr * 64 + c8 * 8);
    }
#pragma unroll
    for (int s = 0; s < 4; ++s) {
      int rr = s * 32 + srow;
      int word = w0 + rr;
      int k = k0 + c8 * 8;
      const u16* src = (k < EDIM) ? (Xd + ((size_t)t * NW + word) * EDIM + k)
                                  : (hpd + (size_t)word * HDIM + (k - EDIM));
      gload16(src, ldsB + rr * 64 + c8 * 8);
    }
    __syncthreads();
#pragma unroll
    for (int kk = 0; kk < 2; ++kk) {
      const int ko = kk * 32 + (lane >> 4) * 8;
      bf16x8 af[4], bfr[4];
#pragma unroll
      for (int mi = 0; mi < 4; ++mi)
        af[mi] = ldfrag(ldsA + (wm * 64 + mi * 16 + (lane & 15)) * 64 + ko);
#pragma unroll
      for (int ni = 0; ni < 4; ++ni)
        bfr[ni] = ldfrag(ldsB + (wn * 64 + ni * 16 + (lane & 15)) * 64 + ko);
#pragma unroll
      for (int mi = 0; mi < 4; ++mi)
#pragma unroll
        for (int ni = 0; ni < 4; ++ni)
          acc[mi][ni] = __builtin_amdgcn_mfma_f32_16x16x32_bf16(af[mi], bfr[ni], acc[mi][ni], 0, 0, 0);
    }
    __syncthreads();
  }

  // epilogue: per-lane LSTM update (regs 0..3 of each acc = i,f,g,o for one (unit,word))
  const float* bcd = bcat + dir * G4;
  float* cd = cst + (size_t)dir * HDIM * NW;
  u16* hstage = ldsA;   // reuse: [128 words][32 units]
#pragma unroll
  for (int mi = 0; mi < 4; ++mi) {
    int ul = wm * 16 + mi * 4 + (lane >> 4);       // local unit 0..31
    int unit = blockIdx.y * 32 + ul;
    float4 bb = *(const float4*)(bcd + 4 * unit);
#pragma unroll
    for (int ni = 0; ni < 4; ++ni) {
      int wl = wn * 64 + ni * 16 + (lane & 15);
      int word = w0 + wl;
      f32x4 a = acc[mi][ni];
      float gi = a[0] + bb.x, gf = a[1] + bb.y, gg = a[2] + bb.z, go = a[3] + bb.w;
      size_t cidx = (size_t)unit * NW + word;
      float c0 = first ? 0.f : cd[cidx];
      float cn = sigf(gf) * c0 + sigf(gi) * tanha(gg);
      float hh = sigf(go) * tanha(cn);
      cd[cidx] = cn;
      hstage[wl * 32 + ul] = f2bf(hh);
    }
  }
  __syncthreads();

  u16* hnd = hnext + (size_t)dir * NW * HDIM;
  const int dirOff = dir ? 0 : HDIM;   // torch order: (reverse, forward)
#pragma unroll
  for (int r = 0; r < 2; ++r) {
    int i4 = tid * 2 + r;              // 0..511
    int wl = i4 >> 2, part = i4 & 3;
    int word = w0 + wl;
    int4 v = ((const int4*)hstage)[i4];
    *(int4*)(hnd + (size_t)word * HDIM + blockIdx.y * 32 + part * 8) = v;
    if (t == lens_s[word] - 1) {
      int orig = perm[word];
      *(int4*)(concat + (size_t)orig * 1024 + dirOff + blockIdx.y * 32 + part * 8) = v;
    }
  }
}

// ---------------- final projection: out = concat @ Wp^T + bp ----------------
// C[word][hout]: M = 4096 words, N = 512, K = 1024. grid x=32 (words), y=4 (hout)
__global__ __launch_bounds__(256) void proj_kernel(
    const u16* __restrict__ concat, const u16* __restrict__ Wpb,
    const float* __restrict__ bp, float* __restrict__ out) {
  __shared__ u16 ldsA[128 * 64];
  __shared__ u16 ldsB[128 * 64];

  const int tid = threadIdx.x;
  const int lane = tid & 63;
  const int wid = tid >> 6;
  const int wm = wid >> 1, wn = wid & 1;
  const int m0 = blockIdx.x * 128;   // word base
  const int n0 = blockIdx.y * 128;   // hout base

  f32x4 acc[4][4];
#pragma unroll
  for (int i = 0; i < 4; ++i)
#pragma unroll
    for (int j = 0; j < 4; ++j) acc[i][j] = (f32x4){0.f, 0.f, 0.f, 0.f};

  const int srow = tid >> 3;
  const int c8 = tid & 7;

  for (int kit = 0; kit < 16; ++kit) {
    const int k0 = kit * 64;
#pragma unroll
    for (int s = 0; s < 4; ++s) {
      int rr = s * 32 + srow;
      gload16(concat + (size_t)(m0 + rr) * 1024 + k0 + c8 * 8, ldsA + rr * 64 + c8 * 8);
      gload16(Wpb + (size_t)(n0 + rr) * 1024 + k0 + c8 * 8, ldsB + rr * 64 + c8 * 8);
    }
    __syncthreads();
#pragma unroll
    for (int kk = 0; kk < 2; ++kk) {
      const int ko = kk * 32 + (lane >> 4) * 8;
      bf16x8 af[4], bfr[4];
#pragma unroll
      for (int mi = 0; mi < 4; ++mi)
        af[mi] = ldfrag(ldsA + (wm * 64 + mi * 16 + (lane & 15)) * 64 + ko);
#pragma unroll
      for (int ni = 0; ni < 4; ++ni)
        bfr[ni] = ldfrag(ldsB + (wn * 64 + ni * 16 + (lane & 15)) * 64 + ko);
#pragma unroll
      for (int mi = 0; mi < 4; ++mi)
#pragma unroll
        for (int ni = 0; ni < 4; ++ni)
          acc[mi][ni] = __builtin_amdgcn_mfma_f32_16x16x32_bf16(af[mi], bfr[ni], acc[mi][ni], 0, 0, 0);
    }
    __syncthreads();
  }

  float bpv[4];
#pragma unroll
  for (int ni = 0; ni < 4; ++ni) bpv[ni] = bp[n0 + wn * 64 + ni * 16 + (lane & 15)];
#pragma unroll
  for (int mi = 0; mi < 4; ++mi)
#pragma unroll
    for (int ni = 0; ni < 4; ++ni)
#pragma unroll
      for (int rg = 0; rg < 4; ++rg) {
        int word = m0 + wm * 64 + mi * 16 + (lane >> 4) * 4 + rg;
        int hout = n0 + wn * 64 + ni * 16 + (lane & 15);
        out[(size_t)word * HDIM + hout] = acc[mi][ni][rg] + bpv[ni];
      }
}

extern "C" void kernel_launch(void* const* d_in, const int* in_sizes, int n_in,
                              void* d_out, int out_size, void* d_ws, size_t ws_size,
                              hipStream_t stream) {
  const int* chars = (const int*)d_in[0];
  const int* lens  = (const int*)d_in[1];
  const float* emb = (const float*)d_in[2];
  const float* Wih_f = (const float*)d_in[3];
  const float* Whh_f = (const float*)d_in[4];
  const float* bih_f = (const float*)d_in[5];
  const float* bhh_f = (const float*)d_in[6];
  const float* Wih_b = (const float*)d_in[7];
  const float* Whh_b = (const float*)d_in[8];
  const float* bih_b = (const float*)d_in[9];
  const float* bhh_b = (const float*)d_in[10];
  const float* Wp = (const float*)d_in[11];
  const float* bp = (const float*)d_in[12];
  float* out = (float*)d_out;

  char* ws = (char*)d_ws;
  size_t o = 0;
  u16* Wcat = (u16*)(ws + o);  o += (size_t)2 * G4 * KREC * 2;       // 5.25 MB
  float* bcat = (float*)(ws + o); o += (size_t)2 * G4 * 4;           // 16 KB
  u16* Wpb = (u16*)(ws + o);   o += (size_t)HDIM * 1024 * 2;         // 1 MB
  u16* Xf = (u16*)(ws + o);    o += (size_t)LMAX * NW * EDIM * 2;    // 16 MB
  u16* Xb = (u16*)(ws + o);    o += (size_t)LMAX * NW * EDIM * 2;    // 16 MB
  u16* hbuf = (u16*)(ws + o);  o += (size_t)2 * 2 * NW * HDIM * 2;   // 16 MB (ping x dir)
  float* cst = (float*)(ws + o); o += (size_t)2 * HDIM * NW * 4;     // 16 MB
  u16* concat = (u16*)(ws + o); o += (size_t)NW * 1024 * 2;          // 8 MB
  int* perm = (int*)(ws + o);  o += (size_t)NW * 4;                  // 16 KB
  int* lens_s = (int*)(ws + o); o += (size_t)NW * 4;                 // 16 KB
  int* nactive = (int*)(ws + o); o += 64;

  sort_kernel<<<1, 256, 0, stream>>>(lens, perm, lens_s, nactive);

  prep_kernel<<<5648, 256, 0, stream>>>(chars, perm, lens_s, emb,
      Wih_f, Whh_f, bih_f, bhh_f, Wih_b, Whh_b, bih_b, bhh_b, Wp,
      Wcat, bcat, Wpb, Xf, Xb);

  const size_t hping = (size_t)2 * NW * HDIM;
  for (int t = 0; t < LMAX; ++t) {
    int ping = t & 1;
    u16* hprev = hbuf + (size_t)ping * hping;
    u16* hnext = hbuf + (size_t)(ping ^ 1) * hping;
    int nIter = (t == 0) ? 2 : 10;   // K = 128 (x only) at t=0, else 640
    step_kernel<<<dim3(32, 16, 2), 256, 0, stream>>>(
        Wcat, bcat, Xf, Xb, hprev, hnext, cst, concat,
        perm, lens_s, nactive, t, nIter, t == 0 ? 1 : 0);
  }

  proj_kernel<<<dim3(32, 4), 256, 0, stream>>>(concat, Wpb, bp, out);
}

// Round 6
// 728.082 us; speedup vs baseline: 1.1693x; 1.1693x over previous
//
#include <hip/hip_runtime.h>

typedef unsigned short u16;
typedef __bf16 bf16x8 __attribute__((ext_vector_type(8)));
typedef float f32x4 __attribute__((ext_vector_type(4)));

#define NW 4096      // B*W words
#define HDIM 512
#define EDIM 128
#define G4 2048      // 4*H
#define LMAX 16
#define KREC 640     // E + H

__device__ __forceinline__ u16 f2bf(float f) {
  unsigned u = __float_as_uint(f);
  u += 0x7FFFu + ((u >> 16) & 1u);
  return (u16)(u >> 16);
}

__device__ __forceinline__ float sigf(float x) { return 1.f / (1.f + __expf(-x)); }
__device__ __forceinline__ float tanha(float x) {
  float ax = fabsf(x);
  float e = __expf(2.f * ax);
  float t = 1.f - 2.f / (e + 1.f);
  return x < 0.f ? -t : t;
}

__device__ __forceinline__ void gload16(const void* g, void* l) {
  __builtin_amdgcn_global_load_lds((const __attribute__((address_space(1))) void*)g,
                                   (__attribute__((address_space(3))) void*)l, 16, 0, 0);
}

union V16 { int4 i; bf16x8 b; };
__device__ __forceinline__ bf16x8 ldfrag(const u16* p) {
  V16 v; v.i = *(const int4*)p; return v.b;
}

// ---------------- sort: bucket words by length (descending) ----------------
__global__ __launch_bounds__(256) void sort_kernel(
    const int* __restrict__ lens,
    int* __restrict__ perm, int* __restrict__ lens_s, int* __restrict__ nactive) {
  __shared__ int cnt[LMAX + 1];
  __shared__ int start[LMAX + 1];
  __shared__ int cursor[LMAX + 1];
  int tid = threadIdx.x;
  if (tid <= LMAX) cnt[tid] = 0;
  __syncthreads();
  for (int w = tid; w < NW; w += 256) atomicAdd(&cnt[lens[w]], 1);
  __syncthreads();
  if (tid == 0) {
    int acc = 0;
    for (int l = LMAX; l >= 1; --l) { start[l] = acc; acc += cnt[l]; }
    start[0] = acc;
  }
  __syncthreads();
  if (tid <= LMAX) cursor[tid] = start[tid];
  if (tid < LMAX) nactive[tid] = start[tid];
  __syncthreads();
  for (int w = tid; w < NW; w += 256) {
    int l = lens[w];
    int pos = atomicAdd(&cursor[l], 1);
    perm[pos] = w;
    lens_s[pos] = l;
  }
}

// ---------------- prep ----------------
// All bf16 operand buffers are stored PRE-SWIZZLED: 16B chunk c of row r goes to
// chunk position (c ^ (r&7)) within its 8-chunk group. Row parity survives into
// the LDS tiles, so global_load_lds staging stays LINEAR and only the ds_read
// side applies the XOR (rule #21: source-permutation == read-permutation).
__global__ __launch_bounds__(256) void prep_kernel(
    const int* __restrict__ chars,
    const int* __restrict__ perm, const int* __restrict__ lens_s,
    const float* __restrict__ emb,
    const float* __restrict__ Wih_f, const float* __restrict__ Whh_f,
    const float* __restrict__ bih_f, const float* __restrict__ bhh_f,
    const float* __restrict__ Wih_b, const float* __restrict__ Whh_b,
    const float* __restrict__ bih_b, const float* __restrict__ bhh_b,
    const float* __restrict__ Wp,
    u16* __restrict__ Wcat, float* __restrict__ bcat, u16* __restrict__ Wpb,
    u16* __restrict__ Xf, u16* __restrict__ Xb) {
  int idx = blockIdx.x * 256 + threadIdx.x;
  if (idx < 327680) {                       // Wcat
    int d = idx / (2048 * 80);
    int r = idx % (2048 * 80);
    int p = r / 80, c8 = r % 80;
    int unit = p >> 2, gate = p & 3;
    int orig = gate * 512 + unit;
    const float* Wih = d ? Wih_b : Wih_f;
    const float* Whh = d ? Whh_b : Whh_f;
    int k = c8 * 8;
    const float* src = (k < EDIM) ? (Wih + (size_t)orig * EDIM + k)
                                  : (Whh + (size_t)orig * HDIM + (k - EDIM));
    union { u16 u[8]; int4 v; } t;
#pragma unroll
    for (int j = 0; j < 8; ++j) t.u[j] = f2bf(src[j]);
    *(int4*)(Wcat + ((size_t)d * G4 + p) * KREC + ((c8 ^ (p & 7)) * 8)) = t.v;
  } else if (idx < 331776) {                // bcat
    int r = idx - 327680;
    int d = r / G4, p = r % G4;
    int unit = p >> 2, gate = p & 3;
    int orig = gate * 512 + unit;
    bcat[d * G4 + p] = d ? (bih_b[orig] + bhh_b[orig]) : (bih_f[orig] + bhh_f[orig]);
  } else if (idx < 397312) {                // Wpb
    int r = idx - 331776;
    int row = r >> 7, c8 = r & 127;
    union { u16 u[8]; int4 v; } t;
#pragma unroll
    for (int j = 0; j < 8; ++j) t.u[j] = f2bf(Wp[(size_t)row * 1024 + c8 * 8 + j]);
    *(int4*)(Wpb + (size_t)row * 1024 + ((c8 ^ (row & 7)) * 8)) = t.v;
  } else {                                  // X gathers (sorted space)
    int r = idx - 397312;
    int tw = r >> 4, l = r & 15;
    int t = tw >> 12, s = tw & (NW - 1);
    int e8 = l * 8;
    int w = perm[s];
    int len = lens_s[s];
    int cf = chars[w * LMAX + t];
    int tb = len - 1 - t; if (tb < 0) tb = 0;
    int cb = chars[w * LMAX + tb];
    union { u16 u[8]; int4 v; } vf, vb;
#pragma unroll
    for (int j = 0; j < 8; ++j) {
      vf.u[j] = f2bf(emb[(size_t)cf * EDIM + e8 + j]);
      vb.u[j] = f2bf(emb[(size_t)cb * EDIM + e8 + j]);
    }
    size_t o = ((size_t)t * NW + s) * EDIM + ((l ^ (s & 7)) * 8);
    *(int4*)(Xf + o) = vf.v;
    *(int4*)(Xb + o) = vb.v;
  }
}

// ---------------- per-step fused GEMM + LSTM update (sorted word space) ----------------
// Double-buffered 2-phase prefetch: one raw s_barrier per K-iter; vmcnt(0) drain
// happens AFTER compute so the just-issued next-tile loads hide under MFMA.
__global__ __launch_bounds__(256) void step_kernel(
    const u16* __restrict__ Wcat, const float* __restrict__ bcat,
    const u16* __restrict__ Xf, const u16* __restrict__ Xb,
    const u16* __restrict__ hprev, u16* __restrict__ hnext,
    float* __restrict__ cst, u16* __restrict__ concat,
    const int* __restrict__ perm, const int* __restrict__ lens_s,
    const int* __restrict__ nactive, int t, int nIter, int first) {
  const int w0 = blockIdx.x * 128;
  if (w0 >= nactive[t]) return;

  __shared__ u16 ldsA[2][128 * 64];
  __shared__ u16 ldsB[2][128 * 64];

  const int tid = threadIdx.x;
  const int lane = tid & 63;
  const int wid = tid >> 6;
  const int wm = wid >> 1, wn = wid & 1;
  const int dir = blockIdx.z;
  const int m0 = blockIdx.y * 128;

  const u16* Wd = Wcat + (size_t)dir * G4 * KREC;
  const u16* Xd = dir ? Xb : Xf;
  const u16* hpd = hprev + (size_t)dir * NW * HDIM;

  f32x4 acc[4][4];
#pragma unroll
  for (int i = 0; i < 4; ++i)
#pragma unroll
    for (int j = 0; j < 4; ++j) acc[i][j] = (f32x4){0.f, 0.f, 0.f, 0.f};

  const int srow = tid >> 3;     // 0..31
  const int c8 = tid & 7;

  auto STAGE = [&](int buf, int kit) {
    const int k0 = kit * 64;
#pragma unroll
    for (int s = 0; s < 4; ++s) {
      int rr = s * 32 + srow;
      gload16(Wd + (size_t)(m0 + rr) * KREC + k0 + c8 * 8, &ldsA[buf][rr * 64 + c8 * 8]);
    }
#pragma unroll
    for (int s = 0; s < 4; ++s) {
      int rr = s * 32 + srow;
      int word = w0 + rr;
      int k = k0 + c8 * 8;
      const u16* src = (k < EDIM) ? (Xd + ((size_t)t * NW + word) * EDIM + k)
                                  : (hpd + (size_t)word * HDIM + (k - EDIM));
      gload16(src, &ldsB[buf][rr * 64 + c8 * 8]);
    }
  };

  STAGE(0, 0);
  asm volatile("s_waitcnt vmcnt(0)" ::: "memory");
  __builtin_amdgcn_s_barrier();

  const int key = lane & 7;        // swizzle key (row&7 == lane&7 for frag rows)
  int cur = 0;
  for (int kit = 0; kit < nIter; ++kit) {
    if (kit + 1 < nIter) STAGE(cur ^ 1, kit + 1);
#pragma unroll
    for (int kk = 0; kk < 2; ++kk) {
      const int pc = ((kk * 4 + (lane >> 4)) ^ key) * 8;   // swizzled 16B chunk
      bf16x8 af[4], bfr[4];
#pragma unroll
      for (int mi = 0; mi < 4; ++mi)
        af[mi] = ldfrag(&ldsA[cur][(wm * 64 + mi * 16 + (lane & 15)) * 64 + pc]);
#pragma unroll
      for (int ni = 0; ni < 4; ++ni)
        bfr[ni] = ldfrag(&ldsB[cur][(wn * 64 + ni * 16 + (lane & 15)) * 64 + pc]);
#pragma unroll
      for (int mi = 0; mi < 4; ++mi)
#pragma unroll
        for (int ni = 0; ni < 4; ++ni)
          acc[mi][ni] = __builtin_amdgcn_mfma_f32_16x16x32_bf16(af[mi], bfr[ni], acc[mi][ni], 0, 0, 0);
    }
    asm volatile("s_waitcnt vmcnt(0)" ::: "memory");
    __builtin_amdgcn_s_barrier();
    cur ^= 1;
  }

  // epilogue: per-lane LSTM update (regs 0..3 of each acc = i,f,g,o for one (unit,word))
  const float* bcd = bcat + dir * G4;
  float* cd = cst + (size_t)dir * HDIM * NW;
  u16* hstage = &ldsA[0][0];   // reuse: [128 words][32 units]
#pragma unroll
  for (int mi = 0; mi < 4; ++mi) {
    int ul = wm * 16 + mi * 4 + (lane >> 4);       // local unit 0..31
    int unit = blockIdx.y * 32 + ul;
    float4 bb = *(const float4*)(bcd + 4 * unit);
#pragma unroll
    for (int ni = 0; ni < 4; ++ni) {
      int wl = wn * 64 + ni * 16 + (lane & 15);
      int word = w0 + wl;
      f32x4 a = acc[mi][ni];
      float gi = a[0] + bb.x, gf = a[1] + bb.y, gg = a[2] + bb.z, go = a[3] + bb.w;
      size_t cidx = (size_t)unit * NW + word;
      float c0 = first ? 0.f : cd[cidx];
      float cn = sigf(gf) * c0 + sigf(gi) * tanha(gg);
      float hh = sigf(go) * tanha(cn);
      cd[cidx] = cn;
      hstage[wl * 32 + ul] = f2bf(hh);
    }
  }
  __syncthreads();

  u16* hnd = hnext + (size_t)dir * NW * HDIM;
  const int coff = dir ? 0 : 64;   // torch order: (reverse, forward); chunk units
#pragma unroll
  for (int r = 0; r < 2; ++r) {
    int i4 = tid * 2 + r;              // 0..511
    int wl = i4 >> 2, part = i4 & 3;
    int word = w0 + wl;
    int4 v = ((const int4*)hstage)[i4];
    int c2 = blockIdx.y * 4 + part;    // 16B chunk index within h row
    *(int4*)(hnd + (size_t)word * HDIM + ((c2 ^ (word & 7)) * 8)) = v;
    if (t == lens_s[word] - 1) {
      int orig = perm[word];
      int cc = coff + blockIdx.y * 4 + part;
      *(int4*)(concat + (size_t)orig * 1024 + ((cc ^ (orig & 7)) * 8)) = v;
    }
  }
}

// ---------------- final projection: out = concat @ Wp^T + bp ----------------
__global__ __launch_bounds__(256) void proj_kernel(
    const u16* __restrict__ concat, const u16* __restrict__ Wpb,
    const float* __restrict__ bp, float* __restrict__ out) {
  __shared__ u16 ldsA[128 * 64];
  __shared__ u16 ldsB[128 * 64];

  const int tid = threadIdx.x;
  const int lane = tid & 63;
  const int wid = tid >> 6;
  const int wm = wid >> 1, wn = wid & 1;
  const int m0 = blockIdx.x * 128;
  const int n0 = blockIdx.y * 128;

  f32x4 acc[4][4];
#pragma unroll
  for (int i = 0; i < 4; ++i)
#pragma unroll
    for (int j = 0; j < 4; ++j) acc[i][j] = (f32x4){0.f, 0.f, 0.f, 0.f};

  const int srow = tid >> 3;
  const int c8 = tid & 7;
  const int key = lane & 7;

  for (int kit = 0; kit < 16; ++kit) {
    const int k0 = kit * 64;
#pragma unroll
    for (int s = 0; s < 4; ++s) {
      int rr = s * 32 + srow;
      gload16(concat + (size_t)(m0 + rr) * 1024 + k0 + c8 * 8, ldsA + rr * 64 + c8 * 8);
      gload16(Wpb + (size_t)(n0 + rr) * 1024 + k0 + c8 * 8, ldsB + rr * 64 + c8 * 8);
    }
    __syncthreads();
#pragma unroll
    for (int kk = 0; kk < 2; ++kk) {
      const int pc = ((kk * 4 + (lane >> 4)) ^ key) * 8;
      bf16x8 af[4], bfr[4];
#pragma unroll
      for (int mi = 0; mi < 4; ++mi)
        af[mi] = ldfrag(ldsA + (wm * 64 + mi * 16 + (lane & 15)) * 64 + pc);
#pragma unroll
      for (int ni = 0; ni < 4; ++ni)
        bfr[ni] = ldfrag(ldsB + (wn * 64 + ni * 16 + (lane & 15)) * 64 + pc);
#pragma unroll
      for (int mi = 0; mi < 4; ++mi)
#pragma unroll
        for (int ni = 0; ni < 4; ++ni)
          acc[mi][ni] = __builtin_amdgcn_mfma_f32_16x16x32_bf16(af[mi], bfr[ni], acc[mi][ni], 0, 0, 0);
    }
    __syncthreads();
  }

  float bpv[4];
#pragma unroll
  for (int ni = 0; ni < 4; ++ni) bpv[ni] = bp[n0 + wn * 64 + ni * 16 + (lane & 15)];
#pragma unroll
  for (int mi = 0; mi < 4; ++mi)
#pragma unroll
    for (int ni = 0; ni < 4; ++ni)
#pragma unroll
      for (int rg = 0; rg < 4; ++rg) {
        int word = m0 + wm * 64 + mi * 16 + (lane >> 4) * 4 + rg;
        int hout = n0 + wn * 64 + ni * 16 + (lane & 15);
        out[(size_t)word * HDIM + hout] = acc[mi][ni][rg] + bpv[ni];
      }
}

extern "C" void kernel_launch(void* const* d_in, const int* in_sizes, int n_in,
                              void* d_out, int out_size, void* d_ws, size_t ws_size,
                              hipStream_t stream) {
  const int* chars = (const int*)d_in[0];
  const int* lens  = (const int*)d_in[1];
  const float* emb = (const float*)d_in[2];
  const float* Wih_f = (const float*)d_in[3];
  const float* Whh_f = (const float*)d_in[4];
  const float* bih_f = (const float*)d_in[5];
  const float* bhh_f = (const float*)d_in[6];
  const float* Wih_b = (const float*)d_in[7];
  const float* Whh_b = (const float*)d_in[8];
  const float* bih_b = (const float*)d_in[9];
  const float* bhh_b = (const float*)d_in[10];
  const float* Wp = (const float*)d_in[11];
  const float* bp = (const float*)d_in[12];
  float* out = (float*)d_out;

  char* ws = (char*)d_ws;
  size_t o = 0;
  u16* Wcat = (u16*)(ws + o);  o += (size_t)2 * G4 * KREC * 2;
  float* bcat = (float*)(ws + o); o += (size_t)2 * G4 * 4;
  u16* Wpb = (u16*)(ws + o);   o += (size_t)HDIM * 1024 * 2;
  u16* Xf = (u16*)(ws + o);    o += (size_t)LMAX * NW * EDIM * 2;
  u16* Xb = (u16*)(ws + o);    o += (size_t)LMAX * NW * EDIM * 2;
  u16* hbuf = (u16*)(ws + o);  o += (size_t)2 * 2 * NW * HDIM * 2;
  float* cst = (float*)(ws + o); o += (size_t)2 * HDIM * NW * 4;
  u16* concat = (u16*)(ws + o); o += (size_t)NW * 1024 * 2;
  int* perm = (int*)(ws + o);  o += (size_t)NW * 4;
  int* lens_s = (int*)(ws + o); o += (size_t)NW * 4;
  int* nactive = (int*)(ws + o); o += 64;

  sort_kernel<<<1, 256, 0, stream>>>(lens, perm, lens_s, nactive);

  prep_kernel<<<5648, 256, 0, stream>>>(chars, perm, lens_s, emb,
      Wih_f, Whh_f, bih_f, bhh_f, Wih_b, Whh_b, bih_b, bhh_b, Wp,
      Wcat, bcat, Wpb, Xf, Xb);

  const size_t hping = (size_t)2 * NW * HDIM;
  for (int t = 0; t < LMAX; ++t) {
    int ping = t & 1;
    u16* hprev = hbuf + (size_t)ping * hping;
    u16* hnext = hbuf + (size_t)(ping ^ 1) * hping;
    int nIter = (t == 0) ? 2 : 10;   // K = 128 (x only) at t=0, else 640
    step_kernel<<<dim3(32, 16, 2), 256, 0, stream>>>(
        Wcat, bcat, Xf, Xb, hprev, hnext, cst, concat,
        perm, lens_s, nactive, t, nIter, t == 0 ? 1 : 0);
  }

  proj_kernel<<<dim3(32, 4), 256, 0, stream>>>(concat, Wpb, bp, out);
}